// Round 6
// baseline (399.268 us; speedup 1.0000x reference)
//
#include <hip/hip_runtime.h>
#include <math.h>

#define N_NODES    100000
#define N_EDGES    3200000
#define N_GRAPHS   128
#define IN_DIM     128
#define HID        64
#define OUT_DIM    128
#define NBKT       391          // ceil(N_NODES / 256)
#define BIN_BLOCKS 512
#define E_PER_BIN  6250         // N_EDGES / BIN_BLOCKS (exact)
#define LMAX       10240        // max bucket records staged in LDS (40KB)

typedef unsigned short ushort_t;

__device__ __forceinline__ ushort_t f2bf(float f) {
    unsigned int u = __float_as_uint(f);
    u += 0x7FFFu + ((u >> 16) & 1u);        // round to nearest even
    return (ushort_t)(u >> 16);
}

// ---------------- per-bucket edge histogram (bucket = dst >> 8) -------------
__global__ __launch_bounds__(256) void k_bkt_hist(const int* __restrict__ dst,
                                                  int* __restrict__ bkt_cnt) {
    __shared__ int hist[NBKT];
    int t = threadIdx.x;
    for (int b = t; b < NBKT; b += 256) hist[b] = 0;
    __syncthreads();
    int e0 = blockIdx.x * E_PER_BIN;
    for (int e = e0 + t; e < e0 + E_PER_BIN; e += 256)
        atomicAdd(&hist[dst[e] >> 8], 1);
    __syncthreads();
    for (int b = t; b < NBKT; b += 256) {
        int h = hist[b];
        if (h) atomicAdd(&bkt_cnt[b], h);
    }
}

// ---------------- exclusive scan over bucket counts (single block) ----------
__global__ void k_scan_bkt(const int* __restrict__ bkt_cnt,
                           int* __restrict__ bkt_ptr, int* __restrict__ bkt_cur) {
    __shared__ int s[512];
    int t = threadIdx.x;
    int v = (t < NBKT) ? bkt_cnt[t] : 0;
    s[t] = v; __syncthreads();
    for (int d = 1; d < 512; d <<= 1) {
        int add = (t >= d) ? s[t - d] : 0;
        __syncthreads();
        s[t] += add;
        __syncthreads();
    }
    int excl = s[t] - v;
    if (t <= NBKT) bkt_ptr[t] = excl;       // bkt_ptr[NBKT] = N_EDGES
    if (t < NBKT)  bkt_cur[t] = excl;
}

// ---------------- multisplit binning: recs[pos] = (src<<8)|dst_local --------
__global__ __launch_bounds__(256) void k_bin(const int* __restrict__ src,
                                             const int* __restrict__ dst,
                                             int* __restrict__ bkt_cursor,
                                             unsigned int* __restrict__ recs) {
    __shared__ int hist[NBKT];
    __shared__ int base[NBKT];
    int t = threadIdx.x;
    int e0 = blockIdx.x * E_PER_BIN;
    int e1 = e0 + E_PER_BIN;                 // exact: 512*6250 = 3.2M
    for (int b = t; b < NBKT; b += 256) hist[b] = 0;
    __syncthreads();
    for (int e = e0 + t; e < e1; e += 256)
        atomicAdd(&hist[dst[e] >> 8], 1);
    __syncthreads();
    for (int b = t; b < NBKT; b += 256) {
        int h = hist[b];
        base[b] = h ? atomicAdd(&bkt_cursor[b], h) : 0;
        hist[b] = 0;
    }
    __syncthreads();
    for (int e = e0 + t; e < e1; e += 256) {
        int d = dst[e];
        int b = d >> 8;
        int pos = base[b] + atomicAdd(&hist[b], 1);
        recs[pos] = ((unsigned int)src[e] << 8) | (unsigned int)(d & 255);
    }
}

// -- per-bucket: counts -> row_ptr + dinv + CSR placement + per-node SORT ----
// sorting each node's src list makes downstream float sums order-deterministic
__global__ __launch_bounds__(256) void k_csrA(const unsigned int* __restrict__ recs,
                                              const int* __restrict__ bkt_ptr,
                                              int* __restrict__ row_ptr,
                                              float* __restrict__ dinv,
                                              int* __restrict__ csr_src) {
    __shared__ int lcnt[256];
    __shared__ int s[256];
    __shared__ int lcur[256];
    __shared__ int lrecs[LMAX];
    int b = blockIdx.x, t = threadIdx.x;
    int start = bkt_ptr[b], end = bkt_ptr[b + 1];
    int total = end - start;
    lcnt[t] = 0;
    __syncthreads();
    for (int i = start + t; i < end; i += 256)
        atomicAdd(&lcnt[recs[i] & 255u], 1);
    __syncthreads();
    int v = lcnt[t];
    s[t] = v; __syncthreads();
    for (int d = 1; d < 256; d <<= 1) {
        int add = (t >= d) ? s[t - d] : 0;
        __syncthreads();
        s[t] += add;
        __syncthreads();
    }
    int excl = s[t] - v;                     // local exclusive offset
    int n = b * 256 + t;
    if (n <= N_NODES) row_ptr[n] = start + excl;   // n==N_NODES -> N_EDGES
    if (n < N_NODES)  dinv[n] = 1.0f / sqrtf((float)v + 1.0f);
    lcur[t] = excl;
    __syncthreads();
    if (total <= LMAX) {
        // stage bucket records into LDS, split by dst_local
        for (int i = start + t; i < end; i += 256) {
            unsigned int r = recs[i];
            int p = atomicAdd(&lcur[r & 255u], 1);
            lrecs[p] = (int)(r >> 8);
        }
        __syncthreads();
        // per-node insertion sort by src id (equal keys: identical values,
        // order irrelevant) -> deterministic CSR content
        int ls = excl, le = excl + v;
        for (int i = ls + 1; i < le; ++i) {
            int key = lrecs[i];
            int j = i - 1;
            while (j >= ls && lrecs[j] > key) { lrecs[j + 1] = lrecs[j]; --j; }
            lrecs[j + 1] = key;
        }
        __syncthreads();
        for (int i = t; i < total; i += 256)
            csr_src[start + i] = lrecs[i];
    } else {
        // fallback (statistically unreachable): unsorted direct placement
        for (int i = start + t; i < end; i += 256) {
            unsigned int r = recs[i];
            int p = atomicAdd(&lcur[r & 255u], 1);
            csr_src[start + p] = (int)(r >> 8);
        }
    }
}

// -- register-blocked GEMM  Ybf[N,64] = bf16( dinv[n] * (X[N,K] @ W[K,64]) ) --
// 64x64 tile, 16x16 thread grid, 4x4 micro-tile, K staged in 64-chunks
template <int K>
__global__ __launch_bounds__(256) void k_gemm(const float* __restrict__ X,
                                              const float* __restrict__ W,
                                              const float* __restrict__ dinv,
                                              ushort_t* __restrict__ Ybf, int nrows) {
    __shared__ float Xs[64][65];    // +1 pad: Xs[r][k] bank = (r+k)%32
    __shared__ float Ws[64][64];
    int t = threadIdx.x;
    int row0 = blockIdx.x * 64;
    int tc = t & 15, tr = t >> 4;
    int c0 = tc * 4, r0 = tr * 4;
    float acc[4][4] = {};
    for (int kc = 0; kc < K; kc += 64) {
        __syncthreads();
#pragma unroll
        for (int i = 0; i < 16; ++i) {          // stage X tile (coalesced)
            int e = i * 256 + t;
            int r = e >> 6, k = e & 63;
            int gr = row0 + r;
            Xs[r][k] = (gr < nrows) ? X[(size_t)gr * K + kc + k] : 0.0f;
        }
#pragma unroll
        for (int i = 0; i < 16; ++i) {          // stage W chunk (coalesced)
            int e = i * 256 + t;
            int k = e >> 6, c = e & 63;
            Ws[k][c] = W[(size_t)(kc + k) * 64 + c];
        }
        __syncthreads();
#pragma unroll 8
        for (int k = 0; k < 64; ++k) {
            float xv[4];
#pragma unroll
            for (int i = 0; i < 4; ++i) xv[i] = Xs[r0 + i][k];
            const float4 w4 = *(const float4*)&Ws[k][c0];
#pragma unroll
            for (int i = 0; i < 4; ++i) {
                acc[i][0] += xv[i] * w4.x;
                acc[i][1] += xv[i] * w4.y;
                acc[i][2] += xv[i] * w4.z;
                acc[i][3] += xv[i] * w4.w;
            }
        }
    }
#pragma unroll
    for (int i = 0; i < 4; ++i) {
        int gr = row0 + r0 + i;
        if (gr < nrows) {
            float dn = dinv[gr];
            ushort4 o;
            o.x = f2bf(dn * acc[i][0]);
            o.y = f2bf(dn * acc[i][1]);
            o.z = f2bf(dn * acc[i][2]);
            o.w = f2bf(dn * acc[i][3]);
            *(ushort4*)(Ybf + (size_t)gr * 64 + c0) = o;
        }
    }
}

// ---------------- gather (bf16 table) + self-loop + bias + relu -------------
// one wave per node; 8 lanes x uint4 (16B) per 128B row; 8 slots x 2-deep = 16 rows in flight
__global__ __launch_bounds__(256) void k_gather(const ushort_t* __restrict__ xwp,
                                                const float* __restrict__ dinv,
                                                const int* __restrict__ row_ptr,
                                                const int* __restrict__ csr_src,
                                                const float* __restrict__ bias,
                                                float* __restrict__ hout) {
    int wave = threadIdx.x >> 6;
    int lane = threadIdx.x & 63;
    int n = blockIdx.x * 4 + wave;
    if (n >= N_NODES) return;
    int sub = lane >> 3, c8 = (lane & 7) * 8;   // 8 edge-slots, 8 cols/lane
    int start = row_ptr[n], end = row_ptr[n + 1];
    float a[8] = {0.f, 0.f, 0.f, 0.f, 0.f, 0.f, 0.f, 0.f};
    int i = start + sub;
    for (; i + 8 < end; i += 16) {
        int s0 = csr_src[i];
        int s1 = csr_src[i + 8];
        const uint4 v0 = *(const uint4*)(xwp + (size_t)s0 * 64 + c8);
        const uint4 v1 = *(const uint4*)(xwp + (size_t)s1 * 64 + c8);
        a[0] += __uint_as_float(v0.x << 16) + __uint_as_float(v1.x << 16);
        a[1] += __uint_as_float(v0.x & 0xFFFF0000u) + __uint_as_float(v1.x & 0xFFFF0000u);
        a[2] += __uint_as_float(v0.y << 16) + __uint_as_float(v1.y << 16);
        a[3] += __uint_as_float(v0.y & 0xFFFF0000u) + __uint_as_float(v1.y & 0xFFFF0000u);
        a[4] += __uint_as_float(v0.z << 16) + __uint_as_float(v1.z << 16);
        a[5] += __uint_as_float(v0.z & 0xFFFF0000u) + __uint_as_float(v1.z & 0xFFFF0000u);
        a[6] += __uint_as_float(v0.w << 16) + __uint_as_float(v1.w << 16);
        a[7] += __uint_as_float(v0.w & 0xFFFF0000u) + __uint_as_float(v1.w & 0xFFFF0000u);
    }
    if (i < end) {
        int s0 = csr_src[i];
        const uint4 v = *(const uint4*)(xwp + (size_t)s0 * 64 + c8);
        a[0] += __uint_as_float(v.x << 16);
        a[1] += __uint_as_float(v.x & 0xFFFF0000u);
        a[2] += __uint_as_float(v.y << 16);
        a[3] += __uint_as_float(v.y & 0xFFFF0000u);
        a[4] += __uint_as_float(v.z << 16);
        a[5] += __uint_as_float(v.z & 0xFFFF0000u);
        a[6] += __uint_as_float(v.w << 16);
        a[7] += __uint_as_float(v.w & 0xFFFF0000u);
    }
#pragma unroll
    for (int off = 8; off < 64; off <<= 1) {
#pragma unroll
        for (int j = 0; j < 8; ++j) a[j] += __shfl_xor(a[j], off, 64);
    }
    if (sub == 0) {
        float dn = dinv[n];
        const uint4 xn = *(const uint4*)(xwp + (size_t)n * 64 + c8);
        float xnf[8];
        xnf[0] = __uint_as_float(xn.x << 16); xnf[1] = __uint_as_float(xn.x & 0xFFFF0000u);
        xnf[2] = __uint_as_float(xn.y << 16); xnf[3] = __uint_as_float(xn.y & 0xFFFF0000u);
        xnf[4] = __uint_as_float(xn.z << 16); xnf[5] = __uint_as_float(xn.z & 0xFFFF0000u);
        xnf[6] = __uint_as_float(xn.w << 16); xnf[7] = __uint_as_float(xn.w & 0xFFFF0000u);
        float4 b0 = *(const float4*)(bias + c8);
        float4 b1 = *(const float4*)(bias + c8 + 4);
        float4 r0, r1;
        r0.x = fmaxf(dn * (a[0] + xnf[0]) + b0.x, 0.f);
        r0.y = fmaxf(dn * (a[1] + xnf[1]) + b0.y, 0.f);
        r0.z = fmaxf(dn * (a[2] + xnf[2]) + b0.z, 0.f);
        r0.w = fmaxf(dn * (a[3] + xnf[3]) + b0.w, 0.f);
        r1.x = fmaxf(dn * (a[4] + xnf[4]) + b1.x, 0.f);
        r1.y = fmaxf(dn * (a[5] + xnf[5]) + b1.y, 0.f);
        r1.z = fmaxf(dn * (a[6] + xnf[6]) + b1.z, 0.f);
        r1.w = fmaxf(dn * (a[7] + xnf[7]) + b1.w, 0.f);
        *(float4*)(hout + (size_t)n * 64 + c8)     = r0;
        *(float4*)(hout + (size_t)n * 64 + c8 + 4) = r1;
    }
}

// ---------------- mean pool (batch is sorted) ----------------
__device__ __forceinline__ int lower_bound(const int* __restrict__ a, int n, int key) {
    int lo = 0, hi = n;
    while (lo < hi) {
        int mid = (lo + hi) >> 1;
        if (a[mid] < key) lo = mid + 1; else hi = mid;
    }
    return lo;
}

__global__ __launch_bounds__(1024) void k_pool(const float* __restrict__ h,
                                               const int* __restrict__ batch,
                                               float* __restrict__ g) {
    int b = blockIdx.x;
    int t = threadIdx.x, c = t & 63, rg = t >> 6;   // 16 row-groups
    __shared__ float s[16][64];
    int start = lower_bound(batch, N_NODES, b);
    int end   = lower_bound(batch, N_NODES, b + 1);
    float sum = 0.f;
    for (int n = start + rg; n < end; n += 16) sum += h[(size_t)n * 64 + c];
    s[rg][c] = sum;
    __syncthreads();
    if (rg == 0) {
        float tot = 0.f;
#pragma unroll
        for (int k = 0; k < 16; ++k) tot += s[k][c];
        float cntf = (float)(end - start);
        g[b * 64 + c] = tot / fmaxf(cntf, 1.0f);
    }
}

// ---------------- final linear  out[128,128] = g[128,64] @ Wl[64,128] + bl --
__global__ void k_final(const float* __restrict__ g, const float* __restrict__ Wl,
                        const float* __restrict__ bl, float* __restrict__ out) {
    __shared__ float gs[64];
    int row = blockIdx.x, c = threadIdx.x;
    if (c < 64) gs[c] = g[row * 64 + c];
    __syncthreads();
    float acc = bl[c];
#pragma unroll
    for (int k = 0; k < 64; ++k) acc += gs[k] * Wl[k * 128 + c];
    out[row * 128 + c] = acc;
}

extern "C" void kernel_launch(void* const* d_in, const int* in_sizes, int n_in,
                              void* d_out, int out_size, void* d_ws, size_t ws_size,
                              hipStream_t stream) {
    const float* x    = (const float*)d_in[0];
    const int*   ei   = (const int*)d_in[1];
    const int*   batch= (const int*)d_in[2];
    const float* W1   = (const float*)d_in[3];
    const float* b1   = (const float*)d_in[4];
    const float* W2   = (const float*)d_in[5];
    const float* b2   = (const float*)d_in[6];
    const float* Wl   = (const float*)d_in[7];
    const float* bl   = (const float*)d_in[8];
    float* out = (float*)d_out;

    const int* src = ei;
    const int* dst = ei + N_EDGES;

    // workspace layout (offsets 128B aligned; no aliasing)
    char* base = (char*)d_ws;
    float*        dinv     = (float*)(base + 0);           // 400 KB
    int*          row_ptr  = (int*)  (base + 400128);      // 400 KB (N+1)
    int*          bkt_cnt  = (int*)  (base + 800256);      // 2 KB
    int*          bkt_ptr  = (int*)  (base + 802304);      // 2 KB
    int*          bkt_cur  = (int*)  (base + 804352);      // 2 KB
    int*          csr_src  = (int*)  (base + 806400);      // 12.8 MB
    unsigned int* recs     = (unsigned int*)(base + 13606400); // 12.8 MB
    ushort_t*     xwp      = (ushort_t*)(base + 26406400); // 12.8 MB (bf16 table)
    float*        h        = (float*)(base + 39206400);    // 25.6 MB
    float*        g        = (float*)(base + 64806400);    // 32 KB

    hipMemsetAsync(bkt_cnt, 0, NBKT * sizeof(int), stream);
    k_bkt_hist<<<BIN_BLOCKS, 256, 0, stream>>>(dst, bkt_cnt);
    k_scan_bkt<<<1, 512, 0, stream>>>(bkt_cnt, bkt_ptr, bkt_cur);
    k_bin     <<<BIN_BLOCKS, 256, 0, stream>>>(src, dst, bkt_cur, recs);
    k_csrA    <<<NBKT, 256, 0, stream>>>(recs, bkt_ptr, row_ptr, dinv, csr_src);

    const int GEMM_GRID = (N_NODES + 63) / 64;   // 1563

    // layer 1: xwp = bf16(dinv .* (x @ W1)); h = relu(dinv.*(agg + xwp) + b1)
    k_gemm<IN_DIM><<<GEMM_GRID, 256, 0, stream>>>(x, W1, dinv, xwp, N_NODES);
    k_gather<<<(N_NODES + 3) / 4, 256, 0, stream>>>(xwp, dinv, row_ptr, csr_src, b1, h);

    // layer 2 (xwp reused; h overwritten in place by gather2)
    k_gemm<HID><<<GEMM_GRID, 256, 0, stream>>>(h, W2, dinv, xwp, N_NODES);
    k_gather<<<(N_NODES + 3) / 4, 256, 0, stream>>>(xwp, dinv, row_ptr, csr_src, b2, h);

    // pool + final linear
    k_pool <<<N_GRAPHS, 1024, 0, stream>>>(h, batch, g);
    k_final<<<N_GRAPHS, 128, 0, stream>>>(g, Wl, bl, out);
}

// Round 7
// 309.714 us; speedup vs baseline: 1.2892x; 1.2892x over previous
//
#include <hip/hip_runtime.h>
#include <math.h>

#define N_NODES    100000
#define N_EDGES    3200000
#define N_GRAPHS   128
#define IN_DIM     128
#define HID        64
#define OUT_DIM    128
#define NBKT       391          // ceil(N_NODES / 256)
#define BIN_BLOCKS 512
#define E_PER_BIN  6250         // N_EDGES / BIN_BLOCKS (exact)

typedef unsigned short ushort_t;

__device__ __forceinline__ ushort_t f2bf(float f) {
    unsigned int u = __float_as_uint(f);
    u += 0x7FFFu + ((u >> 16) & 1u);        // round to nearest even
    return (ushort_t)(u >> 16);
}

// ------- per-bucket edge histogram (bucket = dst >> 8) + persist matrix -----
__global__ __launch_bounds__(256) void k_bkt_hist(const int* __restrict__ dst,
                                                  int* __restrict__ bkt_cnt,
                                                  int* __restrict__ hist_mat) {
    __shared__ int hist[NBKT];
    int t = threadIdx.x;
    for (int b = t; b < NBKT; b += 256) hist[b] = 0;
    __syncthreads();
    int e0 = blockIdx.x * E_PER_BIN;
    for (int e = e0 + t; e < e0 + E_PER_BIN; e += 256)
        atomicAdd(&hist[dst[e] >> 8], 1);
    __syncthreads();
    int* hm = hist_mat + blockIdx.x * NBKT;
    for (int b = t; b < NBKT; b += 256) {
        int h = hist[b];
        hm[b] = h;                          // persisted for k_bin (skip recount)
        if (h) atomicAdd(&bkt_cnt[b], h);
    }
}

// ---------------- exclusive scan over bucket counts (single block) ----------
__global__ void k_scan_bkt(const int* __restrict__ bkt_cnt,
                           int* __restrict__ bkt_ptr, int* __restrict__ bkt_cur) {
    __shared__ int s[512];
    int t = threadIdx.x;
    int v = (t < NBKT) ? bkt_cnt[t] : 0;
    s[t] = v; __syncthreads();
    for (int d = 1; d < 512; d <<= 1) {
        int add = (t >= d) ? s[t - d] : 0;
        __syncthreads();
        s[t] += add;
        __syncthreads();
    }
    int excl = s[t] - v;
    if (t <= NBKT) bkt_ptr[t] = excl;       // bkt_ptr[NBKT] = N_EDGES
    if (t < NBKT)  bkt_cur[t] = excl;
}

// ---------------- multisplit binning: recs[pos] = (src<<8)|dst_local --------
// reuses the persisted per-block histogram; content ORDER is nondeterministic
// (atomic chunk reservation) but downstream sums are order-insensitive (f64)
__global__ __launch_bounds__(256) void k_bin(const int* __restrict__ src,
                                             const int* __restrict__ dst,
                                             const int* __restrict__ hist_mat,
                                             int* __restrict__ bkt_cursor,
                                             unsigned int* __restrict__ recs) {
    __shared__ int hist[NBKT];
    __shared__ int base[NBKT];
    int t = threadIdx.x;
    int e0 = blockIdx.x * E_PER_BIN;
    int e1 = e0 + E_PER_BIN;                 // exact: 512*6250 = 3.2M
    const int* hm = hist_mat + blockIdx.x * NBKT;
    for (int b = t; b < NBKT; b += 256) {
        int h = hm[b];
        base[b] = h ? atomicAdd(&bkt_cursor[b], h) : 0;
        hist[b] = 0;
    }
    __syncthreads();
    for (int e = e0 + t; e < e1; e += 256) {
        int d = dst[e];
        int b = d >> 8;
        int pos = base[b] + atomicAdd(&hist[b], 1);
        recs[pos] = ((unsigned int)src[e] << 8) | (unsigned int)(d & 255);
    }
}

// ---------------- per-bucket: counts -> row_ptr + dinv + CSR placement ------
__global__ __launch_bounds__(256) void k_csrA(const unsigned int* __restrict__ recs,
                                              const int* __restrict__ bkt_ptr,
                                              int* __restrict__ row_ptr,
                                              float* __restrict__ dinv,
                                              int* __restrict__ csr_src) {
    __shared__ int lcnt[256];
    __shared__ int s[256];
    __shared__ int lcur[256];
    int b = blockIdx.x, t = threadIdx.x;
    int start = bkt_ptr[b], end = bkt_ptr[b + 1];
    lcnt[t] = 0;
    __syncthreads();
    for (int i = start + t; i < end; i += 256)
        atomicAdd(&lcnt[recs[i] & 255u], 1);
    __syncthreads();
    int v = lcnt[t];
    s[t] = v; __syncthreads();
    for (int d = 1; d < 256; d <<= 1) {
        int add = (t >= d) ? s[t - d] : 0;
        __syncthreads();
        s[t] += add;
        __syncthreads();
    }
    int excl = s[t] - v;
    int n = b * 256 + t;
    if (n <= N_NODES) row_ptr[n] = start + excl;   // n==N_NODES -> N_EDGES
    if (n < N_NODES)  dinv[n] = 1.0f / sqrtf((float)v + 1.0f);
    lcur[t] = start + excl;
    __syncthreads();
    for (int i = start + t; i < end; i += 256) {
        unsigned int r = recs[i];
        int p = atomicAdd(&lcur[r & 255u], 1);
        csr_src[p] = (int)(r >> 8);
    }
}

// -- register-blocked GEMM  Ybf[N,64] = bf16( dinv[n] * (X[N,K] @ W[K,64]) ) --
// 64x64 tile, 16x16 thread grid, 4x4 micro-tile, K staged in 64-chunks
template <int K>
__global__ __launch_bounds__(256) void k_gemm(const float* __restrict__ X,
                                              const float* __restrict__ W,
                                              const float* __restrict__ dinv,
                                              ushort_t* __restrict__ Ybf, int nrows) {
    __shared__ float Xs[64][65];    // +1 pad: Xs[r][k] bank = (r+k)%32
    __shared__ float Ws[64][64];
    int t = threadIdx.x;
    int row0 = blockIdx.x * 64;
    int tc = t & 15, tr = t >> 4;
    int c0 = tc * 4, r0 = tr * 4;
    float acc[4][4] = {};
    for (int kc = 0; kc < K; kc += 64) {
        __syncthreads();
#pragma unroll
        for (int i = 0; i < 16; ++i) {          // stage X tile (coalesced)
            int e = i * 256 + t;
            int r = e >> 6, k = e & 63;
            int gr = row0 + r;
            Xs[r][k] = (gr < nrows) ? X[(size_t)gr * K + kc + k] : 0.0f;
        }
#pragma unroll
        for (int i = 0; i < 16; ++i) {          // stage W chunk (coalesced)
            int e = i * 256 + t;
            int k = e >> 6, c = e & 63;
            Ws[k][c] = W[(size_t)(kc + k) * 64 + c];
        }
        __syncthreads();
#pragma unroll 8
        for (int k = 0; k < 64; ++k) {
            float xv[4];
#pragma unroll
            for (int i = 0; i < 4; ++i) xv[i] = Xs[r0 + i][k];
            const float4 w4 = *(const float4*)&Ws[k][c0];
#pragma unroll
            for (int i = 0; i < 4; ++i) {
                acc[i][0] += xv[i] * w4.x;
                acc[i][1] += xv[i] * w4.y;
                acc[i][2] += xv[i] * w4.z;
                acc[i][3] += xv[i] * w4.w;
            }
        }
    }
#pragma unroll
    for (int i = 0; i < 4; ++i) {
        int gr = row0 + r0 + i;
        if (gr < nrows) {
            float dn = dinv[gr];
            ushort4 o;
            o.x = f2bf(dn * acc[i][0]);
            o.y = f2bf(dn * acc[i][1]);
            o.z = f2bf(dn * acc[i][2]);
            o.w = f2bf(dn * acc[i][3]);
            *(ushort4*)(Ybf + (size_t)gr * 64 + c0) = o;
        }
    }
}

// ---------------- gather (bf16 table) + self-loop + bias + relu -------------
// one wave per node; 8 lanes x uint4 per 128B row; 8 slots x 2-deep in flight.
// f64 accumulation: bf16 addends in a 52-bit mantissa -> reorder perturbation
// ~1e-12, so the nondeterministic CSR order cannot move the output.
__global__ __launch_bounds__(256) void k_gather(const ushort_t* __restrict__ xwp,
                                                const float* __restrict__ dinv,
                                                const int* __restrict__ row_ptr,
                                                const int* __restrict__ csr_src,
                                                const float* __restrict__ bias,
                                                float* __restrict__ hout) {
    int wave = threadIdx.x >> 6;
    int lane = threadIdx.x & 63;
    int n = blockIdx.x * 4 + wave;
    if (n >= N_NODES) return;
    int sub = lane >> 3, c8 = (lane & 7) * 8;   // 8 edge-slots, 8 cols/lane
    int start = row_ptr[n], end = row_ptr[n + 1];
    double a[8] = {0.0, 0.0, 0.0, 0.0, 0.0, 0.0, 0.0, 0.0};
    int i = start + sub;
    for (; i + 8 < end; i += 16) {
        int s0 = csr_src[i];
        int s1 = csr_src[i + 8];
        const uint4 v0 = *(const uint4*)(xwp + (size_t)s0 * 64 + c8);
        const uint4 v1 = *(const uint4*)(xwp + (size_t)s1 * 64 + c8);
        a[0] += (double)__uint_as_float(v0.x << 16) + (double)__uint_as_float(v1.x << 16);
        a[1] += (double)__uint_as_float(v0.x & 0xFFFF0000u) + (double)__uint_as_float(v1.x & 0xFFFF0000u);
        a[2] += (double)__uint_as_float(v0.y << 16) + (double)__uint_as_float(v1.y << 16);
        a[3] += (double)__uint_as_float(v0.y & 0xFFFF0000u) + (double)__uint_as_float(v1.y & 0xFFFF0000u);
        a[4] += (double)__uint_as_float(v0.z << 16) + (double)__uint_as_float(v1.z << 16);
        a[5] += (double)__uint_as_float(v0.z & 0xFFFF0000u) + (double)__uint_as_float(v1.z & 0xFFFF0000u);
        a[6] += (double)__uint_as_float(v0.w << 16) + (double)__uint_as_float(v1.w << 16);
        a[7] += (double)__uint_as_float(v0.w & 0xFFFF0000u) + (double)__uint_as_float(v1.w & 0xFFFF0000u);
    }
    if (i < end) {
        int s0 = csr_src[i];
        const uint4 v = *(const uint4*)(xwp + (size_t)s0 * 64 + c8);
        a[0] += (double)__uint_as_float(v.x << 16);
        a[1] += (double)__uint_as_float(v.x & 0xFFFF0000u);
        a[2] += (double)__uint_as_float(v.y << 16);
        a[3] += (double)__uint_as_float(v.y & 0xFFFF0000u);
        a[4] += (double)__uint_as_float(v.z << 16);
        a[5] += (double)__uint_as_float(v.z & 0xFFFF0000u);
        a[6] += (double)__uint_as_float(v.w << 16);
        a[7] += (double)__uint_as_float(v.w & 0xFFFF0000u);
    }
#pragma unroll
    for (int off = 8; off < 64; off <<= 1) {
#pragma unroll
        for (int j = 0; j < 8; ++j) a[j] += __shfl_xor(a[j], off, 64);
    }
    if (sub == 0) {
        float dn = dinv[n];
        const uint4 xn = *(const uint4*)(xwp + (size_t)n * 64 + c8);
        float xnf[8];
        xnf[0] = __uint_as_float(xn.x << 16); xnf[1] = __uint_as_float(xn.x & 0xFFFF0000u);
        xnf[2] = __uint_as_float(xn.y << 16); xnf[3] = __uint_as_float(xn.y & 0xFFFF0000u);
        xnf[4] = __uint_as_float(xn.z << 16); xnf[5] = __uint_as_float(xn.z & 0xFFFF0000u);
        xnf[6] = __uint_as_float(xn.w << 16); xnf[7] = __uint_as_float(xn.w & 0xFFFF0000u);
        float4 b0 = *(const float4*)(bias + c8);
        float4 b1 = *(const float4*)(bias + c8 + 4);
        float4 r0, r1;
        r0.x = fmaxf(dn * ((float)a[0] + xnf[0]) + b0.x, 0.f);
        r0.y = fmaxf(dn * ((float)a[1] + xnf[1]) + b0.y, 0.f);
        r0.z = fmaxf(dn * ((float)a[2] + xnf[2]) + b0.z, 0.f);
        r0.w = fmaxf(dn * ((float)a[3] + xnf[3]) + b0.w, 0.f);
        r1.x = fmaxf(dn * ((float)a[4] + xnf[4]) + b1.x, 0.f);
        r1.y = fmaxf(dn * ((float)a[5] + xnf[5]) + b1.y, 0.f);
        r1.z = fmaxf(dn * ((float)a[6] + xnf[6]) + b1.z, 0.f);
        r1.w = fmaxf(dn * ((float)a[7] + xnf[7]) + b1.w, 0.f);
        *(float4*)(hout + (size_t)n * 64 + c8)     = r0;
        *(float4*)(hout + (size_t)n * 64 + c8 + 4) = r1;
    }
}

// ---------------- mean pool (batch is sorted) ----------------
__device__ __forceinline__ int lower_bound(const int* __restrict__ a, int n, int key) {
    int lo = 0, hi = n;
    while (lo < hi) {
        int mid = (lo + hi) >> 1;
        if (a[mid] < key) lo = mid + 1; else hi = mid;
    }
    return lo;
}

__global__ __launch_bounds__(1024) void k_pool(const float* __restrict__ h,
                                               const int* __restrict__ batch,
                                               float* __restrict__ g) {
    int b = blockIdx.x;
    int t = threadIdx.x, c = t & 63, rg = t >> 6;   // 16 row-groups
    __shared__ float s[16][64];
    int start = lower_bound(batch, N_NODES, b);
    int end   = lower_bound(batch, N_NODES, b + 1);
    float sum = 0.f;
    for (int n = start + rg; n < end; n += 16) sum += h[(size_t)n * 64 + c];
    s[rg][c] = sum;
    __syncthreads();
    if (rg == 0) {
        float tot = 0.f;
#pragma unroll
        for (int k = 0; k < 16; ++k) tot += s[k][c];
        float cntf = (float)(end - start);
        g[b * 64 + c] = tot / fmaxf(cntf, 1.0f);
    }
}

// ---------------- final linear  out[128,128] = g[128,64] @ Wl[64,128] + bl --
__global__ void k_final(const float* __restrict__ g, const float* __restrict__ Wl,
                        const float* __restrict__ bl, float* __restrict__ out) {
    __shared__ float gs[64];
    int row = blockIdx.x, c = threadIdx.x;
    if (c < 64) gs[c] = g[row * 64 + c];
    __syncthreads();
    float acc = bl[c];
#pragma unroll
    for (int k = 0; k < 64; ++k) acc += gs[k] * Wl[k * 128 + c];
    out[row * 128 + c] = acc;
}

extern "C" void kernel_launch(void* const* d_in, const int* in_sizes, int n_in,
                              void* d_out, int out_size, void* d_ws, size_t ws_size,
                              hipStream_t stream) {
    const float* x    = (const float*)d_in[0];
    const int*   ei   = (const int*)d_in[1];
    const int*   batch= (const int*)d_in[2];
    const float* W1   = (const float*)d_in[3];
    const float* b1   = (const float*)d_in[4];
    const float* W2   = (const float*)d_in[5];
    const float* b2   = (const float*)d_in[6];
    const float* Wl   = (const float*)d_in[7];
    const float* bl   = (const float*)d_in[8];
    float* out = (float*)d_out;

    const int* src = ei;
    const int* dst = ei + N_EDGES;

    // workspace layout (offsets 128B aligned)
    char* base = (char*)d_ws;
    float*        dinv     = (float*)(base + 0);               // 400 KB
    int*          row_ptr  = (int*)  (base + 400128);          // 400 KB (N+1)
    int*          bkt_cnt  = (int*)  (base + 800256);          // 2 KB
    int*          bkt_ptr  = (int*)  (base + 802304);          // 2 KB
    int*          bkt_cur  = (int*)  (base + 804352);          // 2 KB
    int*          hist_mat = (int*)  (base + 806400);          // 800 KB (512x391)
    int*          csr_src  = (int*)  (base + 1607168);         // 12.8 MB
    ushort_t*     xwp      = (ushort_t*)(base + 14407168);     // 12.8 MB (bf16 table)
    float*        h        = (float*)(base + 27207168);        // 25.6 MB
    float*        g        = (float*)(base + 52807168);        // 32 KB
    // recs aliases xwp: fully consumed by k_csrA before k_gemm writes xwp
    unsigned int* recs     = (unsigned int*)xwp;

    hipMemsetAsync(bkt_cnt, 0, NBKT * sizeof(int), stream);
    k_bkt_hist<<<BIN_BLOCKS, 256, 0, stream>>>(dst, bkt_cnt, hist_mat);
    k_scan_bkt<<<1, 512, 0, stream>>>(bkt_cnt, bkt_ptr, bkt_cur);
    k_bin     <<<BIN_BLOCKS, 256, 0, stream>>>(src, dst, hist_mat, bkt_cur, recs);
    k_csrA    <<<NBKT, 256, 0, stream>>>(recs, bkt_ptr, row_ptr, dinv, csr_src);

    const int GEMM_GRID = (N_NODES + 63) / 64;   // 1563

    // layer 1: xwp = bf16(dinv .* (x @ W1)); h = relu(dinv.*(agg + xwp) + b1)
    k_gemm<IN_DIM><<<GEMM_GRID, 256, 0, stream>>>(x, W1, dinv, xwp, N_NODES);
    k_gather<<<(N_NODES + 3) / 4, 256, 0, stream>>>(xwp, dinv, row_ptr, csr_src, b1, h);

    // layer 2 (xwp reused; h overwritten in place by gather2)
    k_gemm<HID><<<GEMM_GRID, 256, 0, stream>>>(h, W2, dinv, xwp, N_NODES);
    k_gather<<<(N_NODES + 3) / 4, 256, 0, stream>>>(xwp, dinv, row_ptr, csr_src, b2, h);

    // pool + final linear
    k_pool <<<N_GRAPHS, 1024, 0, stream>>>(h, batch, g);
    k_final<<<N_GRAPHS, 128, 0, stream>>>(g, Wl, bl, out);
}